// Round 1
// baseline (3012.546 us; speedup 1.0000x reference)
//
#include <hip/hip_runtime.h>
#include <math.h>

// MoIE transformer block, f32 end-to-end (precision required by sign-gated masks).
// B=4, S=2048, D=1024.
#define Dd 1024
#define Ss 2048
#define NBATCH 4
#define BM 128
#define BN 128
#define BK 16
#define LDP 132   // padded LDS row stride: 132 floats = 528B, 16B-multiple, conflict-free transposed stores

static constexpr float LN_EPS_ = 1e-5f;
static constexpr float GATE_EPS_ = 1e-9f;
static constexpr float SCALE_ = 1.0f / 32.0f;   // 1/sqrt(1024)

__device__ __forceinline__ float silu_f(float v) { return v / (1.0f + __expf(-v)); }

// ---------------- block reductions (256 threads = 4 waves) ----------------
__device__ __forceinline__ float2 block_sum2(float2 v) {
#pragma unroll
  for (int o = 32; o > 0; o >>= 1) { v.x += __shfl_down(v.x, o); v.y += __shfl_down(v.y, o); }
  __shared__ float2 sm2[4];
  if ((threadIdx.x & 63) == 0) sm2[threadIdx.x >> 6] = v;
  __syncthreads();
  float2 r; r.x = sm2[0].x + sm2[1].x + sm2[2].x + sm2[3].x;
  r.y = sm2[0].y + sm2[1].y + sm2[2].y + sm2[3].y;
  __syncthreads();
  return r;
}
__device__ __forceinline__ float block_sum1(float v) {
#pragma unroll
  for (int o = 32; o > 0; o >>= 1) v += __shfl_down(v, o);
  __shared__ float sm1[4];
  if ((threadIdx.x & 63) == 0) sm1[threadIdx.x >> 6] = v;
  __syncthreads();
  float r = sm1[0] + sm1[1] + sm1[2] + sm1[3];
  __syncthreads();
  return r;
}
__device__ __forceinline__ float block_max1(float v) {
#pragma unroll
  for (int o = 32; o > 0; o >>= 1) v = fmaxf(v, __shfl_down(v, o));
  __shared__ float smm[4];
  if ((threadIdx.x & 63) == 0) smm[threadIdx.x >> 6] = v;
  __syncthreads();
  float r = fmaxf(fmaxf(smm[0], smm[1]), fmaxf(smm[2], smm[3]));
  __syncthreads();
  return r;
}

// ---------------- small elementwise kernels ----------------
__global__ __launch_bounds__(256) void k_cost(const float* __restrict__ gate, float* __restrict__ cost) {
  int n = blockIdx.x;
  const float* g = gate + (size_t)n * Dd;
  float m = 0.f;
  for (int i = threadIdx.x; i < Dd; i += 256) m = fmaxf(m, fabsf(g[i]));
  m = block_max1(m);
  float inv = 1.0f / (m + GATE_EPS_);
  for (int i = threadIdx.x; i < Dd; i += 256) cost[(size_t)n * Dd + i] = g[i] * inv;
}

__global__ __launch_bounds__(256) void k_ln_x(const float* __restrict__ x, const float* __restrict__ g,
                                              const float* __restrict__ b, float* __restrict__ h) {
  size_t row = blockIdx.x;
  float4 v = ((const float4*)(x + row * Dd))[threadIdx.x];
  float2 s = { v.x + v.y + v.z + v.w, v.x*v.x + v.y*v.y + v.z*v.z + v.w*v.w };
  s = block_sum2(s);
  float mean = s.x * (1.0f / Dd);
  float var  = s.y * (1.0f / Dd) - mean * mean;
  float rs = rsqrtf(var + LN_EPS_);
  float4 gg = ((const float4*)g)[threadIdx.x];
  float4 bb = ((const float4*)b)[threadIdx.x];
  float4 o;
  o.x = (v.x - mean) * rs * gg.x + bb.x;
  o.y = (v.y - mean) * rs * gg.y + bb.y;
  o.z = (v.z - mean) * rs * gg.z + bb.z;
  o.w = (v.w - mean) * rs * gg.w + bb.w;
  ((float4*)(h + row * Dd))[threadIdx.x] = o;
}

// in-place: ps[row] = proto_w[row] + LN(ps[row]) * pln_g[n] + pln_b[n]
__global__ __launch_bounds__(256) void k_pln(float* __restrict__ ps, const float* __restrict__ proto_w,
                                             const float* __restrict__ pg, const float* __restrict__ pb) {
  size_t row = blockIdx.x;       // 0..4095 ; n = row>>10
  int n = (int)(row >> 10);
  float4 v = ((const float4*)(ps + row * Dd))[threadIdx.x];
  float2 s = { v.x + v.y + v.z + v.w, v.x*v.x + v.y*v.y + v.z*v.z + v.w*v.w };
  s = block_sum2(s);
  float mean = s.x * (1.0f / Dd);
  float var  = s.y * (1.0f / Dd) - mean * mean;
  float rs = rsqrtf(var + LN_EPS_);
  float4 gg = ((const float4*)(pg + (size_t)n * Dd))[threadIdx.x];
  float4 bb = ((const float4*)(pb + (size_t)n * Dd))[threadIdx.x];
  float4 pw = ((const float4*)(proto_w + row * Dd))[threadIdx.x];
  float4 o;
  o.x = (v.x - mean) * rs * gg.x + bb.x + pw.x;
  o.y = (v.y - mean) * rs * gg.y + bb.y + pw.y;
  o.z = (v.z - mean) * rs * gg.z + bb.z + pw.z;
  o.w = (v.w - mean) * rs * gg.w + bb.w + pw.w;
  ((float4*)(ps + row * Dd))[threadIdx.x] = o;
}

// ---------------- GEMM helpers (shared tile config) ----------------
// 256 threads = 16x16; thread tile 8x8 split as 2x2 blocks of 4x4 at offsets {0,64}.
#define MICRO_FMA(ACC, AR, BR)                                            \
  _Pragma("unroll") for (int i = 0; i < 4; ++i) {                         \
    _Pragma("unroll") for (int j = 0; j < 4; ++j) {                       \
      ACC[0][0][i][j] = fmaf(AR[i],     BR[j],     ACC[0][0][i][j]);      \
      ACC[0][1][i][j] = fmaf(AR[i],     BR[4 + j], ACC[0][1][i][j]);      \
      ACC[1][0][i][j] = fmaf(AR[4 + i], BR[j],     ACC[1][0][i][j]);      \
      ACC[1][1][i][j] = fmaf(AR[4 + i], BR[4 + j], ACC[1][1][i][j]);      \
    }                                                                     \
  }

#define XPOSE_STORE(SM, V0, V1)                                           \
  SM[sk + 0][sr] = V0.x; SM[sk + 1][sr] = V0.y;                           \
  SM[sk + 2][sr] = V0.z; SM[sk + 3][sr] = V0.w;                           \
  SM[sk + 0][64 + sr] = V1.x; SM[sk + 1][64 + sr] = V1.y;                 \
  SM[sk + 2][64 + sr] = V1.z; SM[sk + 3][64 + sr] = V1.w;

// C = A * B^T * scale.  A: [M x K] lda=K.  B: [N x K] ldb=K.  causal: skip blocks fully above diag.
__global__ __launch_bounds__(256) void gemm_bt(const float* __restrict__ Ab, const float* __restrict__ Bb,
                                               float* __restrict__ Cb, int K, int ldc, float scale, int causal,
                                               size_t aZ, size_t bZ, size_t cZ) {
  const int m0 = blockIdx.x * BM, n0 = blockIdx.y * BN;
  if (causal && n0 >= m0 + BM) return;
  const float* A = Ab + (size_t)blockIdx.z * aZ;
  const float* B = Bb + (size_t)blockIdx.z * bZ;
  float* Cc = Cb + (size_t)blockIdx.z * cZ;

  __shared__ float As[BK][LDP];
  __shared__ float Bs[BK][LDP];
  const int tid = threadIdx.x, tx = tid & 15, ty = tid >> 4;
  const int sr = tid >> 2, sk = (tid & 3) << 2;

  const float* pA0 = A + (size_t)(m0 + sr) * K + sk;
  const float* pA1 = A + (size_t)(m0 + 64 + sr) * K + sk;
  const float* pB0 = B + (size_t)(n0 + sr) * K + sk;
  const float* pB1 = B + (size_t)(n0 + 64 + sr) * K + sk;

  float acc[2][2][4][4] = {};
  float4 a0 = *(const float4*)pA0, a1 = *(const float4*)pA1;
  float4 b0 = *(const float4*)pB0, b1 = *(const float4*)pB1;

  const int nk = K / BK;
  for (int kt = 0; kt < nk; ++kt) {
    __syncthreads();
    XPOSE_STORE(As, a0, a1)
    XPOSE_STORE(Bs, b0, b1)
    __syncthreads();
    if (kt + 1 < nk) {
      pA0 += BK; pA1 += BK; pB0 += BK; pB1 += BK;
      a0 = *(const float4*)pA0; a1 = *(const float4*)pA1;
      b0 = *(const float4*)pB0; b1 = *(const float4*)pB1;
    }
#pragma unroll
    for (int k = 0; k < BK; ++k) {
      float4 x0 = *(const float4*)&As[k][ty * 4];
      float4 x1 = *(const float4*)&As[k][64 + ty * 4];
      float4 y0 = *(const float4*)&Bs[k][tx * 4];
      float4 y1 = *(const float4*)&Bs[k][64 + tx * 4];
      float ar[8] = { x0.x, x0.y, x0.z, x0.w, x1.x, x1.y, x1.z, x1.w };
      float br[8] = { y0.x, y0.y, y0.z, y0.w, y1.x, y1.y, y1.z, y1.w };
      MICRO_FMA(acc, ar, br)
    }
  }
#pragma unroll
  for (int ri = 0; ri < 2; ++ri)
#pragma unroll
    for (int i = 0; i < 4; ++i) {
      size_t r = (size_t)(m0 + ri * 64 + ty * 4 + i);
#pragma unroll
      for (int ci = 0; ci < 2; ++ci) {
        float4 w;
        w.x = acc[ri][ci][i][0] * scale;
        w.y = acc[ri][ci][i][1] * scale;
        w.z = acc[ri][ci][i][2] * scale;
        w.w = acc[ri][ci][i][3] * scale;
        *(float4*)&Cc[r * (size_t)ldc + n0 + ci * 64 + tx * 4] = w;
      }
    }
}

// dual GEMM: acc1 = A*B1^T, acc2 = A*B2^T  (A-tile loaded once). Epilogue: silu/mask -> qkv.
__global__ __launch_bounds__(256) void k_qkv(const float* __restrict__ hh, const float* __restrict__ mu_w,
                                             const float* __restrict__ mu_b, const float* __restrict__ ps,
                                             const float* __restrict__ cost, float* __restrict__ qkv,
                                             int b0, int Cc) {
  const int z = blockIdx.z;
  const int n = z / Cc, cb = z - n * Cc;
  const float* A  = hh + (size_t)(b0 + cb) * Ss * Dd;
  const float* B1 = mu_w + (size_t)n * Dd * Dd;
  const float* B2 = ps   + (size_t)n * Dd * Dd;
  float* Co = qkv + ((size_t)n * Cc + cb) * (size_t)Ss * Dd;
  const int m0 = blockIdx.x * BM, n0 = blockIdx.y * BN;

  __shared__ float As[BK][LDP], B1s[BK][LDP], B2s[BK][LDP];
  const int tid = threadIdx.x, tx = tid & 15, ty = tid >> 4;
  const int sr = tid >> 2, sk = (tid & 3) << 2;

  const float* pA0 = A + (size_t)(m0 + sr) * Dd + sk;
  const float* pA1 = A + (size_t)(m0 + 64 + sr) * Dd + sk;
  const float* p10 = B1 + (size_t)(n0 + sr) * Dd + sk;
  const float* p11 = B1 + (size_t)(n0 + 64 + sr) * Dd + sk;
  const float* p20 = B2 + (size_t)(n0 + sr) * Dd + sk;
  const float* p21 = B2 + (size_t)(n0 + 64 + sr) * Dd + sk;

  float acc1[2][2][4][4] = {}, acc2[2][2][4][4] = {};
  float4 a0 = *(const float4*)pA0, a1 = *(const float4*)pA1;
  float4 c0 = *(const float4*)p10, c1 = *(const float4*)p11;
  float4 d0 = *(const float4*)p20, d1 = *(const float4*)p21;

  const int nk = Dd / BK;
  for (int kt = 0; kt < nk; ++kt) {
    __syncthreads();
    XPOSE_STORE(As, a0, a1)
    XPOSE_STORE(B1s, c0, c1)
    XPOSE_STORE(B2s, d0, d1)
    __syncthreads();
    if (kt + 1 < nk) {
      pA0 += BK; pA1 += BK; p10 += BK; p11 += BK; p20 += BK; p21 += BK;
      a0 = *(const float4*)pA0; a1 = *(const float4*)pA1;
      c0 = *(const float4*)p10; c1 = *(const float4*)p11;
      d0 = *(const float4*)p20; d1 = *(const float4*)p21;
    }
#pragma unroll
    for (int k = 0; k < BK; ++k) {
      float4 x0 = *(const float4*)&As[k][ty * 4];
      float4 x1 = *(const float4*)&As[k][64 + ty * 4];
      float4 y0 = *(const float4*)&B1s[k][tx * 4];
      float4 y1 = *(const float4*)&B1s[k][64 + tx * 4];
      float4 z0 = *(const float4*)&B2s[k][tx * 4];
      float4 z1 = *(const float4*)&B2s[k][64 + tx * 4];
      float ar[8] = { x0.x, x0.y, x0.z, x0.w, x1.x, x1.y, x1.z, x1.w };
      float br[8] = { y0.x, y0.y, y0.z, y0.w, y1.x, y1.y, y1.z, y1.w };
      float cr[8] = { z0.x, z0.y, z0.z, z0.w, z1.x, z1.y, z1.z, z1.w };
      MICRO_FMA(acc1, ar, br)
      MICRO_FMA(acc2, ar, cr)
    }
  }
  float4 bb[2], cc[2];
#pragma unroll
  for (int ci = 0; ci < 2; ++ci) {
    bb[ci] = *(const float4*)&mu_b[(size_t)n * Dd + n0 + ci * 64 + tx * 4];
    cc[ci] = *(const float4*)&cost[(size_t)n * Dd + n0 + ci * 64 + tx * 4];
  }
#pragma unroll
  for (int ri = 0; ri < 2; ++ri)
#pragma unroll
    for (int i = 0; i < 4; ++i) {
      size_t r = (size_t)(m0 + ri * 64 + ty * 4 + i);
#pragma unroll
      for (int ci = 0; ci < 2; ++ci) {
        float4 w;
        w.x = (fmaf(acc2[ri][ci][i][0], SCALE_, -cc[ci].x) > 0.f) ? silu_f(acc1[ri][ci][i][0] + bb[ci].x) : 0.f;
        w.y = (fmaf(acc2[ri][ci][i][1], SCALE_, -cc[ci].y) > 0.f) ? silu_f(acc1[ri][ci][i][1] + bb[ci].y) : 0.f;
        w.z = (fmaf(acc2[ri][ci][i][2], SCALE_, -cc[ci].z) > 0.f) ? silu_f(acc1[ri][ci][i][2] + bb[ci].z) : 0.f;
        w.w = (fmaf(acc2[ri][ci][i][3], SCALE_, -cc[ci].w) > 0.f) ? silu_f(acc1[ri][ci][i][3] + bb[ci].w) : 0.f;
        *(float4*)&Co[r * Dd + n0 + ci * 64 + tx * 4] = w;
      }
    }
}

// dual GEMM on attn_out; epilogue: out = x + silu(acc1+b3) * ((acc2*scale - cost3) > 0)
__global__ __launch_bounds__(256) void k_out(const float* __restrict__ ao, const float* __restrict__ w3,
                                             const float* __restrict__ b3, const float* __restrict__ ps3,
                                             const float* __restrict__ cost3, const float* __restrict__ x,
                                             float* __restrict__ out, int b0, int Cc) {
  const int cb = blockIdx.z;
  const float* A = ao + (size_t)cb * Ss * Dd;
  const float* xr = x + (size_t)(b0 + cb) * Ss * Dd;
  float* o = out + (size_t)(b0 + cb) * Ss * Dd;
  const int m0 = blockIdx.x * BM, n0 = blockIdx.y * BN;

  __shared__ float As[BK][LDP], B1s[BK][LDP], B2s[BK][LDP];
  const int tid = threadIdx.x, tx = tid & 15, ty = tid >> 4;
  const int sr = tid >> 2, sk = (tid & 3) << 2;

  const float* pA0 = A + (size_t)(m0 + sr) * Dd + sk;
  const float* pA1 = A + (size_t)(m0 + 64 + sr) * Dd + sk;
  const float* p10 = w3 + (size_t)(n0 + sr) * Dd + sk;
  const float* p11 = w3 + (size_t)(n0 + 64 + sr) * Dd + sk;
  const float* p20 = ps3 + (size_t)(n0 + sr) * Dd + sk;
  const float* p21 = ps3 + (size_t)(n0 + 64 + sr) * Dd + sk;

  float acc1[2][2][4][4] = {}, acc2[2][2][4][4] = {};
  float4 a0 = *(const float4*)pA0, a1 = *(const float4*)pA1;
  float4 c0 = *(const float4*)p10, c1 = *(const float4*)p11;
  float4 d0 = *(const float4*)p20, d1 = *(const float4*)p21;

  const int nk = Dd / BK;
  for (int kt = 0; kt < nk; ++kt) {
    __syncthreads();
    XPOSE_STORE(As, a0, a1)
    XPOSE_STORE(B1s, c0, c1)
    XPOSE_STORE(B2s, d0, d1)
    __syncthreads();
    if (kt + 1 < nk) {
      pA0 += BK; pA1 += BK; p10 += BK; p11 += BK; p20 += BK; p21 += BK;
      a0 = *(const float4*)pA0; a1 = *(const float4*)pA1;
      c0 = *(const float4*)p10; c1 = *(const float4*)p11;
      d0 = *(const float4*)p20; d1 = *(const float4*)p21;
    }
#pragma unroll
    for (int k = 0; k < BK; ++k) {
      float4 x0 = *(const float4*)&As[k][ty * 4];
      float4 x1 = *(const float4*)&As[k][64 + ty * 4];
      float4 y0 = *(const float4*)&B1s[k][tx * 4];
      float4 y1 = *(const float4*)&B1s[k][64 + tx * 4];
      float4 z0 = *(const float4*)&B2s[k][tx * 4];
      float4 z1 = *(const float4*)&B2s[k][64 + tx * 4];
      float ar[8] = { x0.x, x0.y, x0.z, x0.w, x1.x, x1.y, x1.z, x1.w };
      float br[8] = { y0.x, y0.y, y0.z, y0.w, y1.x, y1.y, y1.z, y1.w };
      float cr[8] = { z0.x, z0.y, z0.z, z0.w, z1.x, z1.y, z1.z, z1.w };
      MICRO_FMA(acc1, ar, br)
      MICRO_FMA(acc2, ar, cr)
    }
  }
  float4 bb[2], cc[2];
#pragma unroll
  for (int ci = 0; ci < 2; ++ci) {
    bb[ci] = *(const float4*)&b3[n0 + ci * 64 + tx * 4];
    cc[ci] = *(const float4*)&cost3[n0 + ci * 64 + tx * 4];
  }
#pragma unroll
  for (int ri = 0; ri < 2; ++ri)
#pragma unroll
    for (int i = 0; i < 4; ++i) {
      size_t r = (size_t)(m0 + ri * 64 + ty * 4 + i);
#pragma unroll
      for (int ci = 0; ci < 2; ++ci) {
        size_t off = r * Dd + n0 + ci * 64 + tx * 4;
        float4 xv = *(const float4*)&xr[off];
        float4 w;
        w.x = xv.x + ((fmaf(acc2[ri][ci][i][0], SCALE_, -cc[ci].x) > 0.f) ? silu_f(acc1[ri][ci][i][0] + bb[ci].x) : 0.f);
        w.y = xv.y + ((fmaf(acc2[ri][ci][i][1], SCALE_, -cc[ci].y) > 0.f) ? silu_f(acc1[ri][ci][i][1] + bb[ci].y) : 0.f);
        w.z = xv.z + ((fmaf(acc2[ri][ci][i][2], SCALE_, -cc[ci].z) > 0.f) ? silu_f(acc1[ri][ci][i][2] + bb[ci].z) : 0.f);
        w.w = xv.w + ((fmaf(acc2[ri][ci][i][3], SCALE_, -cc[ci].w) > 0.f) ? silu_f(acc1[ri][ci][i][3] + bb[ci].w) : 0.f);
        *(float4*)&o[off] = w;
      }
    }
}

// row softmax over scores row q (causal: k<=q), zeros elsewhere
__global__ __launch_bounds__(256) void k_softmax(float* __restrict__ scores) {
  const int q = blockIdx.x, cb = blockIdx.z;
  float* row = scores + (size_t)cb * Ss * Ss + (size_t)q * Ss;
  float4 v0 = ((const float4*)row)[threadIdx.x];
  float4 v1 = ((const float4*)row)[threadIdx.x + 256];
  int b0i = threadIdx.x * 4, b1i = (threadIdx.x + 256) * 4;
  v0.x = (b0i + 0 <= q) ? v0.x : -INFINITY;
  v0.y = (b0i + 1 <= q) ? v0.y : -INFINITY;
  v0.z = (b0i + 2 <= q) ? v0.z : -INFINITY;
  v0.w = (b0i + 3 <= q) ? v0.w : -INFINITY;
  v1.x = (b1i + 0 <= q) ? v1.x : -INFINITY;
  v1.y = (b1i + 1 <= q) ? v1.y : -INFINITY;
  v1.z = (b1i + 2 <= q) ? v1.z : -INFINITY;
  v1.w = (b1i + 3 <= q) ? v1.w : -INFINITY;
  float mx = fmaxf(fmaxf(fmaxf(v0.x, v0.y), fmaxf(v0.z, v0.w)),
                   fmaxf(fmaxf(v1.x, v1.y), fmaxf(v1.z, v1.w)));
  mx = block_max1(mx);
  v0.x = (b0i + 0 <= q) ? __expf(v0.x - mx) : 0.f;
  v0.y = (b0i + 1 <= q) ? __expf(v0.y - mx) : 0.f;
  v0.z = (b0i + 2 <= q) ? __expf(v0.z - mx) : 0.f;
  v0.w = (b0i + 3 <= q) ? __expf(v0.w - mx) : 0.f;
  v1.x = (b1i + 0 <= q) ? __expf(v1.x - mx) : 0.f;
  v1.y = (b1i + 1 <= q) ? __expf(v1.y - mx) : 0.f;
  v1.z = (b1i + 2 <= q) ? __expf(v1.z - mx) : 0.f;
  v1.w = (b1i + 3 <= q) ? __expf(v1.w - mx) : 0.f;
  float s = v0.x + v0.y + v0.z + v0.w + v1.x + v1.y + v1.z + v1.w;
  s = block_sum1(s);
  float inv = 1.0f / s;
  v0.x *= inv; v0.y *= inv; v0.z *= inv; v0.w *= inv;
  v1.x *= inv; v1.y *= inv; v1.z *= inv; v1.w *= inv;
  ((float4*)row)[threadIdx.x] = v0;
  ((float4*)row)[threadIdx.x + 256] = v1;
}

// attn_out = attn @ v.  A: [2048 x 2048] lda=2048. B: [2048 x 1024] ldb=1024 (K-major rows -> direct store).
__global__ __launch_bounds__(256) void k_pv(const float* __restrict__ attn, const float* __restrict__ vbase,
                                            float* __restrict__ ao) {
  const int cb = blockIdx.z;
  const float* A = attn + (size_t)cb * Ss * Ss;
  const float* B = vbase + (size_t)cb * Ss * Dd;
  float* Co = ao + (size_t)cb * Ss * Dd;
  const int m0 = blockIdx.x * BM, n0 = blockIdx.y * BN;

  __shared__ float As[BK][LDP], Bs[BK][LDP];
  const int tid = threadIdx.x, tx = tid & 15, ty = tid >> 4;
  const int sr = tid >> 2, sk = (tid & 3) << 2;       // A staging (transposed)
  const int bk = tid >> 4, bc = (tid & 15) << 2;      // B staging (direct)

  const float* pA0 = A + (size_t)(m0 + sr) * Ss + sk;
  const float* pA1 = A + (size_t)(m0 + 64 + sr) * Ss + sk;
  const float* pB0 = B + (size_t)bk * Dd + n0 + bc;
  const float* pB1 = B + (size_t)bk * Dd + n0 + 64 + bc;

  float acc[2][2][4][4] = {};
  const int nk = (m0 + BM) / BK;   // causal: attn[q,k]=0 for k>q, so only k-tiles up to q-tile end
  float4 a0 = *(const float4*)pA0, a1 = *(const float4*)pA1;
  float4 b0 = *(const float4*)pB0, b1 = *(const float4*)pB1;

  for (int kt = 0; kt < nk; ++kt) {
    __syncthreads();
    XPOSE_STORE(As, a0, a1)
    *(float4*)&Bs[bk][bc] = b0;
    *(float4*)&Bs[bk][64 + bc] = b1;
    __syncthreads();
    if (kt + 1 < nk) {
      pA0 += BK; pA1 += BK; pB0 += (size_t)BK * Dd; pB1 += (size_t)BK * Dd;
      a0 = *(const float4*)pA0; a1 = *(const float4*)pA1;
      b0 = *(const float4*)pB0; b1 = *(const float4*)pB1;
    }
#pragma unroll
    for (int k = 0; k < BK; ++k) {
      float4 x0 = *(const float4*)&As[k][ty * 4];
      float4 x1 = *(const float4*)&As[k][64 + ty * 4];
      float4 y0 = *(const float4*)&Bs[k][tx * 4];
      float4 y1 = *(const float4*)&Bs[k][64 + tx * 4];
      float ar[8] = { x0.x, x0.y, x0.z, x0.w, x1.x, x1.y, x1.z, x1.w };
      float br[8] = { y0.x, y0.y, y0.z, y0.w, y1.x, y1.y, y1.z, y1.w };
      MICRO_FMA(acc, ar, br)
    }
  }
#pragma unroll
  for (int ri = 0; ri < 2; ++ri)
#pragma unroll
    for (int i = 0; i < 4; ++i) {
      size_t r = (size_t)(m0 + ri * 64 + ty * 4 + i);
#pragma unroll
      for (int ci = 0; ci < 2; ++ci) {
        float4 w;
        w.x = acc[ri][ci][i][0];
        w.y = acc[ri][ci][i][1];
        w.z = acc[ri][ci][i][2];
        w.w = acc[ri][ci][i][3];
        *(float4*)&Co[r * Dd + n0 + ci * 64 + tx * 4] = w;
      }
    }
}

extern "C" void kernel_launch(void* const* d_in, const int* in_sizes, int n_in,
                              void* d_out, int out_size, void* d_ws, size_t ws_size,
                              hipStream_t stream) {
  const float* x        = (const float*)d_in[0];
  const float* ln1_g    = (const float*)d_in[1];
  const float* ln1_b    = (const float*)d_in[2];
  const float* mu_w     = (const float*)d_in[3];
  const float* mu_b     = (const float*)d_in[4];
  const float* proto_w  = (const float*)d_in[5];
  const float* gate     = (const float*)d_in[6];
  const float* pt_w     = (const float*)d_in[7];
  const float* pln_g    = (const float*)d_in[8];
  const float* pln_b    = (const float*)d_in[9];
  const float* in_proto = (const float*)d_in[10];
  float* out = (float*)d_out;

  const size_t SD = (size_t)Ss * Dd;   // 2 Mi floats
  const size_t MI = (size_t)Dd * Dd;   // 1 Mi floats

  float* h    = (float*)d_ws;          // 4*SD
  float* ps   = h + 4 * SD;            // 4*MI (prc -> proto_state in place)
  float* cost = ps + 4 * MI;           // 4096
  float* pool = cost + 4096;

  // batches-in-flight: adapt to workspace (C=4 -> ~240MB, C=2 -> ~144MB, C=1 -> ~96MB)
  auto needBytes = [&](size_t c) -> size_t {
    return (4 * SD + 4 * MI + 4096 + c * (3 * SD + (size_t)Ss * Ss + SD)) * sizeof(float);
  };
  int C = (ws_size >= needBytes(4)) ? 4 : (ws_size >= needBytes(2)) ? 2 : 1;

  float* qkv      = pool;                                  // [n][cb] chunks: 3*C*SD
  float* scores   = qkv + 3 * (size_t)C * SD;              // C * Ss * Ss
  float* attn_out = scores + (size_t)C * Ss * Ss;          // C * SD

  k_cost<<<dim3(4), dim3(256), 0, stream>>>(gate, cost);
  k_ln_x<<<dim3(NBATCH * Ss), dim3(256), 0, stream>>>(x, ln1_g, ln1_b, h);
  // prc = in_proto @ pt_w^T  (per n)
  gemm_bt<<<dim3(Dd / BM, Dd / BN, 4), dim3(256), 0, stream>>>(
      in_proto, pt_w, ps, Dd, Dd, 1.0f, 0, MI, MI, MI);
  k_pln<<<dim3(4 * Dd), dim3(256), 0, stream>>>(ps, proto_w, pln_g, pln_b);

  for (int b0 = 0; b0 < NBATCH; b0 += C) {
    k_qkv<<<dim3(Ss / BM, Dd / BN, 3 * C), dim3(256), 0, stream>>>(
        h, mu_w, mu_b, ps, cost, qkv, b0, C);
    // scores = q @ k^T * scale (causal tile skip); q at qkv[0*C+cb], k at qkv[1*C+cb]
    gemm_bt<<<dim3(Ss / BM, Ss / BN, C), dim3(256), 0, stream>>>(
        qkv, qkv + (size_t)C * SD, scores, Dd, Ss, SCALE_, 1, SD, SD, (size_t)Ss * Ss);
    k_softmax<<<dim3(Ss, 1, C), dim3(256), 0, stream>>>(scores);
    k_pv<<<dim3(Ss / BM, Dd / BN, C), dim3(256), 0, stream>>>(
        scores, qkv + 2 * (size_t)C * SD, attn_out);
    k_out<<<dim3(Ss / BM, Dd / BN, C), dim3(256), 0, stream>>>(
        attn_out, mu_w + 3 * MI, mu_b + 3 * Dd, ps + 3 * MI, cost + 3 * Dd, x, out, b0, C);
  }
}

// Round 3
// 1070.779 us; speedup vs baseline: 2.8134x; 2.8134x over previous
//
#include <hip/hip_runtime.h>
#include <math.h>

// MoIE transformer block on MFMA via f16-triple-split f32 emulation.
// B=4, S=2048, D=1024.
#define Dd 1024
#define Ss 2048
#define NBATCH 4

static constexpr size_t SDsz = (size_t)Ss * Dd;   // 2M elems
static constexpr size_t MIsz = (size_t)Dd * Dd;   // 1M elems
static constexpr size_t SSsz = (size_t)Ss * Ss;   // 4M elems
static constexpr float LN_EPS_ = 1e-5f;
static constexpr float GATE_EPS_ = 1e-9f;
static constexpr float SCALE_ = 1.0f / 32.0f;     // 1/sqrt(1024), exact

typedef _Float16 f16;
typedef _Float16 f16x8 __attribute__((ext_vector_type(8)));
typedef _Float16 f16x4 __attribute__((ext_vector_type(4)));
typedef float f32x4 __attribute__((ext_vector_type(4)));

__device__ __forceinline__ float silu_f(float v) { return v / (1.0f + __expf(-v)); }

__device__ __forceinline__ void split3(float x, f16& a, f16& b, f16& c) {
  a = (f16)x; float r = x - (float)a;
  b = (f16)r; float r2 = r - (float)b;
  c = (f16)r2;
}
__device__ __forceinline__ void split2(float x, f16& a, f16& b) {
  a = (f16)x; b = (f16)(x - (float)a);
}

// ---------------- block reductions (256 threads = 4 waves) ----------------
__device__ __forceinline__ float2 block_sum2(float2 v) {
#pragma unroll
  for (int o = 32; o > 0; o >>= 1) { v.x += __shfl_down(v.x, o); v.y += __shfl_down(v.y, o); }
  __shared__ float2 sm2[4];
  if ((threadIdx.x & 63) == 0) sm2[threadIdx.x >> 6] = v;
  __syncthreads();
  float2 r; r.x = sm2[0].x + sm2[1].x + sm2[2].x + sm2[3].x;
  r.y = sm2[0].y + sm2[1].y + sm2[2].y + sm2[3].y;
  __syncthreads();
  return r;
}
__device__ __forceinline__ float block_sum1(float v) {
#pragma unroll
  for (int o = 32; o > 0; o >>= 1) v += __shfl_down(v, o);
  __shared__ float sm1[4];
  if ((threadIdx.x & 63) == 0) sm1[threadIdx.x >> 6] = v;
  __syncthreads();
  float r = sm1[0] + sm1[1] + sm1[2] + sm1[3];
  __syncthreads();
  return r;
}
__device__ __forceinline__ float block_max1(float v) {
#pragma unroll
  for (int o = 32; o > 0; o >>= 1) v = fmaxf(v, __shfl_down(v, o));
  __shared__ float smm[4];
  if ((threadIdx.x & 63) == 0) smm[threadIdx.x >> 6] = v;
  __syncthreads();
  float r = fmaxf(fmaxf(smm[0], smm[1]), fmaxf(smm[2], smm[3]));
  __syncthreads();
  return r;
}

// ---------------- multi-plane MFMA GEMM core ----------------
// acc += sum_{i+j<=MAXSUM} A_i * B_j^T over K; tile 128x128, 4 waves each 64x64.
// LDS rows padded to 40 f16 (80B): 16B-aligned f16x8 accesses, ~2-way bank alias (free).
template<int PLANES, int MAXSUM>
__device__ __forceinline__ void mp_core(
    f16* __restrict__ smem,
    const f16* __restrict__ Ap0, const f16* __restrict__ Ap1, const f16* __restrict__ Ap2,
    const f16* __restrict__ Bp0, const f16* __restrict__ Bp1, const f16* __restrict__ Bp2,
    int lda, int ldb, int m0, int n0, int kt_end, f32x4 acc[4][4]) {
  const f16* Ap[3] = {Ap0, Ap1, Ap2};
  const f16* Bp[3] = {Bp0, Bp1, Bp2};
  const int tid = threadIdx.x;
  const int l = tid & 63;
  const int wv = tid >> 6;
  const int wr = (wv >> 1) * 64, wc = (wv & 1) * 64;
  const int fl = l & 15, fq = l >> 4;
  const int r0 = tid >> 2, kc = (tid & 3) * 8;   // staging: rows r0, r0+64; k-col kc

  f16x8 ra[PLANES][2], rb[PLANES][2];
#pragma unroll
  for (int p = 0; p < PLANES; ++p) {
    ra[p][0] = *(const f16x8*)(Ap[p] + (size_t)(m0 + r0) * lda + kc);
    ra[p][1] = *(const f16x8*)(Ap[p] + (size_t)(m0 + 64 + r0) * lda + kc);
    rb[p][0] = *(const f16x8*)(Bp[p] + (size_t)(n0 + r0) * ldb + kc);
    rb[p][1] = *(const f16x8*)(Bp[p] + (size_t)(n0 + 64 + r0) * ldb + kc);
  }
  for (int kt = 0; kt < kt_end; ++kt) {
    __syncthreads();
#pragma unroll
    for (int p = 0; p < PLANES; ++p) {
      *(f16x8*)(smem + p * 5120 + r0 * 40 + kc) = ra[p][0];
      *(f16x8*)(smem + p * 5120 + (64 + r0) * 40 + kc) = ra[p][1];
      *(f16x8*)(smem + (PLANES + p) * 5120 + r0 * 40 + kc) = rb[p][0];
      *(f16x8*)(smem + (PLANES + p) * 5120 + (64 + r0) * 40 + kc) = rb[p][1];
    }
    __syncthreads();
    if (kt + 1 < kt_end) {
      const int ko = (kt + 1) * 32 + kc;
#pragma unroll
      for (int p = 0; p < PLANES; ++p) {
        ra[p][0] = *(const f16x8*)(Ap[p] + (size_t)(m0 + r0) * lda + ko);
        ra[p][1] = *(const f16x8*)(Ap[p] + (size_t)(m0 + 64 + r0) * lda + ko);
        rb[p][0] = *(const f16x8*)(Bp[p] + (size_t)(n0 + r0) * ldb + ko);
        rb[p][1] = *(const f16x8*)(Bp[p] + (size_t)(n0 + 64 + r0) * ldb + ko);
      }
    }
    f16x8 af[PLANES][4];
#pragma unroll
    for (int p = 0; p < PLANES; ++p)
#pragma unroll
      for (int fr = 0; fr < 4; ++fr)
        af[p][fr] = *(const f16x8*)(smem + p * 5120 + (wr + fr * 16 + fl) * 40 + fq * 8);
#pragma unroll
    for (int fc = 0; fc < 4; ++fc) {
      f16x8 bf[PLANES];
#pragma unroll
      for (int p = 0; p < PLANES; ++p)
        bf[p] = *(const f16x8*)(smem + (PLANES + p) * 5120 + (wc + fc * 16 + fl) * 40 + fq * 8);
#pragma unroll
      for (int i = 0; i < PLANES; ++i)
#pragma unroll
        for (int j = 0; j < PLANES; ++j)
          if (i + j <= MAXSUM) {
#pragma unroll
            for (int fr = 0; fr < 4; ++fr)
              acc[fr][fc] = __builtin_amdgcn_mfma_f32_16x16x32_f16(af[i][fr], bf[j], acc[fr][fc], 0, 0, 0);
          }
    }
  }
}

// epilogue iterator: calls f(row, col, accumulated value) for each of the 64 outputs.
template<class F>
__device__ __forceinline__ void epilogue(const f32x4 acc[4][4], int m0, int n0, F&& f) {
  const int tid = threadIdx.x;
  const int l = tid & 63;
  const int wv = tid >> 6;
  const int wr = (wv >> 1) * 64, wc = (wv & 1) * 64;
  const int fl = l & 15, fq = l >> 4;
#pragma unroll
  for (int fr = 0; fr < 4; ++fr)
#pragma unroll
    for (int fc = 0; fc < 4; ++fc) {
      f32x4 av = acc[fr][fc];
#pragma unroll
      for (int r = 0; r < 4; ++r)
        f(m0 + wr + fr * 16 + fq * 4 + r, n0 + wc + fc * 16 + fl, av[r]);
    }
}

// ---------------- GEMM wrapper kernels ----------------

// prc = in_proto @ pt_w^T per expert (f16x2, 4 products)
__global__ __launch_bounds__(256) void k_prc(const f16* __restrict__ ip0, const f16* __restrict__ ip1,
                                             const f16* __restrict__ pt0, const f16* __restrict__ pt1,
                                             float* __restrict__ prc) {
  __shared__ f16 smem[2 * 2 * 5120];
  const int n = blockIdx.z;
  const int m0 = blockIdx.x * 128, n0 = blockIdx.y * 128;
  const size_t o = (size_t)n * MIsz;
  f32x4 acc[4][4] = {};
  mp_core<2, 2>(smem, ip0 + o, ip1 + o, nullptr, pt0 + o, pt1 + o, nullptr, Dd, Dd, m0, n0, Dd / 32, acc);
  float* Cp = prc + o;
  epilogue(acc, m0, n0, [&](int row, int col, float aval) {
    Cp[(size_t)row * Dd + col] = aval;
  });
}

// comp = silu(h @ mu_w[n]^T + mu_b[n]) -> f16x2 planes (3 products)
__global__ __launch_bounds__(256) void k_comp(const f16* __restrict__ h0, const f16* __restrict__ h1,
                                              const f16* __restrict__ w0, const f16* __restrict__ w1,
                                              const float* __restrict__ mu_b,
                                              f16* __restrict__ comp0, f16* __restrict__ comp1, int C) {
  __shared__ f16 smem[2 * 2 * 5120];
  const int z = blockIdx.z, n = z / C, cb = z - n * C;
  const int m0 = blockIdx.x * 128, n0 = blockIdx.y * 128;
  const size_t ao = (size_t)cb * SDsz, bo = (size_t)n * MIsz;
  f32x4 acc[4][4] = {};
  mp_core<2, 1>(smem, h0 + ao, h1 + ao, nullptr, w0 + bo, w1 + bo, nullptr, Dd, Dd, m0, n0, Dd / 32, acc);
  const float* bp = mu_b + (size_t)n * Dd;
  f16* c0 = comp0 + (size_t)z * SDsz;
  f16* c1 = comp1 + (size_t)z * SDsz;
  epilogue(acc, m0, n0, [&](int row, int col, float aval) {
    float v = silu_f(aval + bp[col]);
    f16 lo, hi; split2(v, lo, hi);
    size_t idx = (size_t)row * Dd + col;
    c0[idx] = lo; c1[idx] = hi;
  });
}

// mv gate: mask = (h@ps[n]^T * scale - cost[n]) > 0 ; qkv planes = mask ? comp : 0  (6 products)
__global__ __launch_bounds__(256) void k_mv(const f16* __restrict__ h0, const f16* __restrict__ h1,
                                            const f16* __restrict__ h2,
                                            const f16* __restrict__ s0, const f16* __restrict__ s1,
                                            const f16* __restrict__ s2, const float* __restrict__ cost,
                                            const f16* __restrict__ comp0, const f16* __restrict__ comp1,
                                            f16* __restrict__ qkvb, int C) {
  __shared__ f16 smem[2 * 3 * 5120];
  const int z = blockIdx.z, n = z / C, cb = z - n * C;
  const int m0 = blockIdx.x * 128, n0 = blockIdx.y * 128;
  const size_t ao = (size_t)cb * SDsz, bo = (size_t)n * MIsz;
  f32x4 acc[4][4] = {};
  mp_core<3, 2>(smem, h0 + ao, h1 + ao, h2 + ao, s0 + bo, s1 + bo, s2 + bo, Dd, Dd, m0, n0, Dd / 32, acc);
  const float* cp = cost + (size_t)n * Dd;
  const f16* c0 = comp0 + (size_t)z * SDsz;
  const f16* c1 = comp1 + (size_t)z * SDsz;
  f16* o0 = qkvb + ((size_t)(2 * n) * C + cb) * SDsz;
  f16* o1 = qkvb + ((size_t)(2 * n + 1) * C + cb) * SDsz;
  epilogue(acc, m0, n0, [&](int row, int col, float aval) {
    size_t idx = (size_t)row * Dd + col;
    bool m = (aval * SCALE_ - cp[col]) > 0.f;
    o0[idx] = m ? c0[idx] : (f16)0.f;
    o1[idx] = m ? c1[idx] : (f16)0.f;
  });
}

// scores = q @ k^T * scale, causal tile-skip (4 products)
__global__ __launch_bounds__(256) void k_scores(const f16* __restrict__ qkvb, float* __restrict__ scores, int C) {
  const int m0 = blockIdx.x * 128, n0 = blockIdx.y * 128;
  if (n0 >= m0 + 128) return;
  __shared__ f16 smem[2 * 2 * 5120];
  const int cb = blockIdx.z;
  const f16* q0 = qkvb + ((size_t)0 * C + cb) * SDsz;
  const f16* q1 = qkvb + ((size_t)1 * C + cb) * SDsz;
  const f16* kk0 = qkvb + ((size_t)2 * C + cb) * SDsz;
  const f16* kk1 = qkvb + ((size_t)3 * C + cb) * SDsz;
  f32x4 acc[4][4] = {};
  mp_core<2, 2>(smem, q0, q1, nullptr, kk0, kk1, nullptr, Dd, Dd, m0, n0, Dd / 32, acc);
  float* Cp = scores + (size_t)cb * SSsz;
  epilogue(acc, m0, n0, [&](int row, int col, float aval) {
    Cp[(size_t)row * Ss + col] = aval * SCALE_;
  });
}

// attn_out = attn @ v (via vT), causal k-bound; split f16x3 planes (4 products)
__global__ __launch_bounds__(256) void k_pv(const f16* __restrict__ a0, const f16* __restrict__ a1,
                                            const f16* __restrict__ vT0, const f16* __restrict__ vT1,
                                            f16* __restrict__ ao0, f16* __restrict__ ao1, f16* __restrict__ ao2) {
  __shared__ f16 smem[2 * 2 * 5120];
  const int cb = blockIdx.z;
  const int m0 = blockIdx.x * 128, n0 = blockIdx.y * 128;
  const f16* A0 = a0 + (size_t)cb * SSsz;
  const f16* A1 = a1 + (size_t)cb * SSsz;
  const f16* B0 = vT0 + (size_t)cb * SDsz;
  const f16* B1 = vT1 + (size_t)cb * SDsz;
  const int kt_end = (m0 + 128) / 32;
  f32x4 acc[4][4] = {};
  mp_core<2, 2>(smem, A0, A1, nullptr, B0, B1, nullptr, Ss, Ss, m0, n0, kt_end, acc);
  f16* p0 = ao0 + (size_t)cb * SDsz;
  f16* p1 = ao1 + (size_t)cb * SDsz;
  f16* p2 = ao2 + (size_t)cb * SDsz;
  epilogue(acc, m0, n0, [&](int row, int col, float aval) {
    f16 x0, x1, x2; split3(aval, x0, x1, x2);
    size_t idx = (size_t)row * Dd + col;
    p0[idx] = x0; p1[idx] = x1; p2[idx] = x2;
  });
}

// c_o = silu(attn_out @ mu_w[3]^T + mu_b[3]) -> f16 plane (3 products)
__global__ __launch_bounds__(256) void k_co(const f16* __restrict__ ao0, const f16* __restrict__ ao1,
                                            const f16* __restrict__ w30, const f16* __restrict__ w31,
                                            const float* __restrict__ b3, f16* __restrict__ co) {
  __shared__ f16 smem[2 * 2 * 5120];
  const int cb = blockIdx.z;
  const int m0 = blockIdx.x * 128, n0 = blockIdx.y * 128;
  const f16* A0 = ao0 + (size_t)cb * SDsz;
  const f16* A1 = ao1 + (size_t)cb * SDsz;
  f32x4 acc[4][4] = {};
  mp_core<2, 1>(smem, A0, A1, nullptr, w30, w31, nullptr, Dd, Dd, m0, n0, Dd / 32, acc);
  f16* cp = co + (size_t)cb * SDsz;
  epilogue(acc, m0, n0, [&](int row, int col, float aval) {
    cp[(size_t)row * Dd + col] = (f16)silu_f(aval + b3[col]);
  });
}

// final: out = x + (attn_out @ ps[3]^T * scale - cost3 > 0 ? c_o : 0)   (6 products)
__global__ __launch_bounds__(256) void k_mvo(const f16* __restrict__ ao0, const f16* __restrict__ ao1,
                                             const f16* __restrict__ ao2,
                                             const f16* __restrict__ s30, const f16* __restrict__ s31,
                                             const f16* __restrict__ s32, const float* __restrict__ cost3,
                                             const f16* __restrict__ co, const float* __restrict__ x,
                                             float* __restrict__ out, int b0) {
  __shared__ f16 smem[2 * 3 * 5120];
  const int cb = blockIdx.z;
  const int m0 = blockIdx.x * 128, n0 = blockIdx.y * 128;
  const f16* A0 = ao0 + (size_t)cb * SDsz;
  const f16* A1 = ao1 + (size_t)cb * SDsz;
  const f16* A2 = ao2 + (size_t)cb * SDsz;
  f32x4 acc[4][4] = {};
  mp_core<3, 2>(smem, A0, A1, A2, s30, s31, s32, Dd, Dd, m0, n0, Dd / 32, acc);
  const f16* cp = co + (size_t)cb * SDsz;
  const float* xp = x + (size_t)(b0 + cb) * SDsz;
  float* op = out + (size_t)(b0 + cb) * SDsz;
  epilogue(acc, m0, n0, [&](int row, int col, float aval) {
    size_t idx = (size_t)row * Dd + col;
    bool m = (aval * SCALE_ - cost3[col]) > 0.f;
    op[idx] = xp[idx] + (m ? (float)cp[idx] : 0.f);
  });
}

// ---------------- elementwise / small kernels ----------------
__global__ __launch_bounds__(256) void k_cost(const float* __restrict__ gate, float* __restrict__ cost) {
  int n = blockIdx.x;
  const float* g = gate + (size_t)n * Dd;
  float m = 0.f;
  for (int i = threadIdx.x; i < Dd; i += 256) m = fmaxf(m, fabsf(g[i]));
  m = block_max1(m);
  float inv = 1.0f / (m + GATE_EPS_);
  for (int i = threadIdx.x; i < Dd; i += 256) cost[(size_t)n * Dd + i] = g[i] * inv;
}

// LN(x) -> f16x3 planes for the current C-group
__global__ __launch_bounds__(256) void k_ln3(const float* __restrict__ x, const float* __restrict__ g,
                                             const float* __restrict__ b, f16* __restrict__ h0,
                                             f16* __restrict__ h1, f16* __restrict__ h2, int b0) {
  size_t row = blockIdx.x;
  const float* xr = x + ((size_t)b0 * Ss + row) * Dd;
  float4 v = ((const float4*)xr)[threadIdx.x];
  float2 s = {v.x + v.y + v.z + v.w, v.x * v.x + v.y * v.y + v.z * v.z + v.w * v.w};
  s = block_sum2(s);
  float mean = s.x * (1.0f / Dd);
  float var = s.y * (1.0f / Dd) - mean * mean;
  float rs = rsqrtf(var + LN_EPS_);
  float4 gg = ((const float4*)g)[threadIdx.x];
  float4 bb = ((const float4*)b)[threadIdx.x];
  float o[4];
  o[0] = (v.x - mean) * rs * gg.x + bb.x;
  o[1] = (v.y - mean) * rs * gg.y + bb.y;
  o[2] = (v.z - mean) * rs * gg.z + bb.z;
  o[3] = (v.w - mean) * rs * gg.w + bb.w;
  f16x4 p0, p1, p2;
#pragma unroll
  for (int j = 0; j < 4; ++j) { f16 a_, b_, c_; split3(o[j], a_, b_, c_); p0[j] = a_; p1[j] = b_; p2[j] = c_; }
  ((f16x4*)(h0 + row * Dd))[threadIdx.x] = p0;
  ((f16x4*)(h1 + row * Dd))[threadIdx.x] = p1;
  ((f16x4*)(h2 + row * Dd))[threadIdx.x] = p2;
}

// ps = proto_w + LN(prc)*pln_g + pln_b -> f16x3 planes
__global__ __launch_bounds__(256) void k_pln3(const float* __restrict__ prc, const float* __restrict__ proto_w,
                                              const float* __restrict__ pg, const float* __restrict__ pb,
                                              f16* __restrict__ s0, f16* __restrict__ s1, f16* __restrict__ s2) {
  size_t row = blockIdx.x;            // 0..4095
  int n = (int)(row >> 10);
  float4 v = ((const float4*)(prc + row * Dd))[threadIdx.x];
  float2 s = {v.x + v.y + v.z + v.w, v.x * v.x + v.y * v.y + v.z * v.z + v.w * v.w};
  s = block_sum2(s);
  float mean = s.x * (1.0f / Dd);
  float var = s.y * (1.0f / Dd) - mean * mean;
  float rs = rsqrtf(var + LN_EPS_);
  float4 gg = ((const float4*)(pg + (size_t)n * Dd))[threadIdx.x];
  float4 bb = ((const float4*)(pb + (size_t)n * Dd))[threadIdx.x];
  float4 pw = ((const float4*)(proto_w + row * Dd))[threadIdx.x];
  float o[4];
  o[0] = (v.x - mean) * rs * gg.x + bb.x + pw.x;
  o[1] = (v.y - mean) * rs * gg.y + bb.y + pw.y;
  o[2] = (v.z - mean) * rs * gg.z + bb.z + pw.z;
  o[3] = (v.w - mean) * rs * gg.w + bb.w + pw.w;
  f16x4 p0, p1, p2;
#pragma unroll
  for (int j = 0; j < 4; ++j) { f16 a_, b_, c_; split3(o[j], a_, b_, c_); p0[j] = a_; p1[j] = b_; p2[j] = c_; }
  ((f16x4*)(s0 + row * Dd))[threadIdx.x] = p0;
  ((f16x4*)(s1 + row * Dd))[threadIdx.x] = p1;
  ((f16x4*)(s2 + row * Dd))[threadIdx.x] = p2;
}

// generic f32 -> f16x2 plane split, grid-strided over float4 chunks
__global__ __launch_bounds__(256) void k_split2(const float* __restrict__ in, f16* __restrict__ p0,
                                                f16* __restrict__ p1, size_t n4) {
  size_t stride = (size_t)gridDim.x * 256;
  for (size_t i = (size_t)blockIdx.x * 256 + threadIdx.x; i < n4; i += stride) {
    float4 v = ((const float4*)in)[i];
    f16x4 lo, hi;
    f16 a_, b_;
    split2(v.x, a_, b_); lo[0] = a_; hi[0] = b_;
    split2(v.y, a_, b_); lo[1] = a_; hi[1] = b_;
    split2(v.z, a_, b_); lo[2] = a_; hi[2] = b_;
    split2(v.w, a_, b_); lo[3] = a_; hi[3] = b_;
    ((f16x4*)p0)[i] = lo;
    ((f16x4*)p1)[i] = hi;
  }
}

// transpose v planes [S][D] -> vT [D][S]
__global__ __launch_bounds__(256) void k_trans(const f16* __restrict__ qkvb, f16* __restrict__ vT0,
                                               f16* __restrict__ vT1, int C) {
  __shared__ f16 t[64][72];
  const int z = blockIdx.z, pl = z & 1, cb = z >> 1;
  const f16* in = qkvb + ((size_t)(4 + pl) * C + cb) * SDsz;
  f16* out = (pl ? vT1 : vT0) + (size_t)cb * SDsz;
  const int s0 = blockIdx.x * 64, d0 = blockIdx.y * 64;
  const int tid = threadIdx.x;
#pragma unroll
  for (int it = 0; it < 2; ++it) {
    int c = tid + it * 256;
    int r = c >> 3, c8 = (c & 7) * 8;
    *(f16x8*)&t[r][c8] = *(const f16x8*)(in + (size_t)(s0 + r) * Dd + d0 + c8);
  }
  __syncthreads();
#pragma unroll
  for (int it = 0; it < 2; ++it) {
    int c = tid + it * 256;
    int r = c >> 3, c8 = (c & 7) * 8;
    f16x8 o;
#pragma unroll
    for (int j = 0; j < 8; ++j) o[j] = t[c8 + j][r];
    *(f16x8*)(out + (size_t)(d0 + r) * Ss + s0 + c8) = o;
  }
}

// row softmax (causal) -> attn f16x2 planes
__global__ __launch_bounds__(256) void k_softmax2(const float* __restrict__ scores, f16* __restrict__ a0,
                                                  f16* __restrict__ a1) {
  const int q = blockIdx.x, cb = blockIdx.z;
  const float* row = scores + (size_t)cb * SSsz + (size_t)q * Ss;
  float4 v0 = ((const float4*)row)[threadIdx.x];
  float4 v1 = ((const float4*)row)[threadIdx.x + 256];
  int b0i = threadIdx.x * 4, b1i = (threadIdx.x + 256) * 4;
  v0.x = (b0i + 0 <= q) ? v0.x : -INFINITY;
  v0.y = (b0i + 1 <= q) ? v0.y : -INFINITY;
  v0.z = (b0i + 2 <= q) ? v0.z : -INFINITY;
  v0.w = (b0i + 3 <= q) ? v0.w : -INFINITY;
  v1.x = (b1i + 0 <= q) ? v1.x : -INFINITY;
  v1.y = (b1i + 1 <= q) ? v1.y : -INFINITY;
  v1.z = (b1i + 2 <= q) ? v1.z : -INFINITY;
  v1.w = (b1i + 3 <= q) ? v1.w : -INFINITY;
  float mx = fmaxf(fmaxf(fmaxf(v0.x, v0.y), fmaxf(v0.z, v0.w)),
                   fmaxf(fmaxf(v1.x, v1.y), fmaxf(v1.z, v1.w)));
  mx = block_max1(mx);
  v0.x = (b0i + 0 <= q) ? __expf(v0.x - mx) : 0.f;
  v0.y = (b0i + 1 <= q) ? __expf(v0.y - mx) : 0.f;
  v0.z = (b0i + 2 <= q) ? __expf(v0.z - mx) : 0.f;
  v0.w = (b0i + 3 <= q) ? __expf(v0.w - mx) : 0.f;
  v1.x = (b1i + 0 <= q) ? __expf(v1.x - mx) : 0.f;
  v1.y = (b1i + 1 <= q) ? __expf(v1.y - mx) : 0.f;
  v1.z = (b1i + 2 <= q) ? __expf(v1.z - mx) : 0.f;
  v1.w = (b1i + 3 <= q) ? __expf(v1.w - mx) : 0.f;
  float s = v0.x + v0.y + v0.z + v0.w + v1.x + v1.y + v1.z + v1.w;
  s = block_sum1(s);
  float inv = 1.0f / s;
  float p0a[4] = {v0.x * inv, v0.y * inv, v0.z * inv, v0.w * inv};
  float p1a[4] = {v1.x * inv, v1.y * inv, v1.z * inv, v1.w * inv};
  f16* r0 = a0 + (size_t)cb * SSsz + (size_t)q * Ss;
  f16* r1 = a1 + (size_t)cb * SSsz + (size_t)q * Ss;
  f16x4 lo0, hi0, lo1, hi1;
#pragma unroll
  for (int j = 0; j < 4; ++j) {
    f16 a_, b_;
    split2(p0a[j], a_, b_); lo0[j] = a_; hi0[j] = b_;
    split2(p1a[j], a_, b_); lo1[j] = a_; hi1[j] = b_;
  }
  ((f16x4*)r0)[threadIdx.x] = lo0;
  ((f16x4*)r0)[threadIdx.x + 256] = lo1;
  ((f16x4*)r1)[threadIdx.x] = hi0;
  ((f16x4*)r1)[threadIdx.x + 256] = hi1;
}

// ---------------- launch ----------------
extern "C" void kernel_launch(void* const* d_in, const int* in_sizes, int n_in,
                              void* d_out, int out_size, void* d_ws, size_t ws_size,
                              hipStream_t stream) {
  const float* x        = (const float*)d_in[0];
  const float* ln1_g    = (const float*)d_in[1];
  const float* ln1_b    = (const float*)d_in[2];
  const float* mu_w     = (const float*)d_in[3];
  const float* mu_b     = (const float*)d_in[4];
  const float* proto_w  = (const float*)d_in[5];
  const float* gate     = (const float*)d_in[6];
  const float* pt_w     = (const float*)d_in[7];
  const float* pln_g    = (const float*)d_in[8];
  const float* pln_b    = (const float*)d_in[9];
  const float* in_proto = (const float*)d_in[10];
  float* out = (float*)d_out;

  uint8_t* base = (uint8_t*)d_ws;
  size_t off = 0;
  auto take = [&](size_t b) -> uint8_t* {
    uint8_t* p = base + off;
    off = (off + b + 255) & ~(size_t)255;
    return p;
  };
  const size_t SDb = SDsz * 2;  // bytes per f16 batch-plane (4MB)
  // persistent
  f16* w0  = (f16*)take(4 * MIsz * 2);
  f16* w1  = (f16*)take(4 * MIsz * 2);
  f16* ps0 = (f16*)take(4 * MIsz * 2);
  f16* ps1 = (f16*)take(4 * MIsz * 2);
  f16* ps2 = (f16*)take(4 * MIsz * 2);
  float* cost = (float*)take(4096 * 4);
  const size_t poolOff = off;

  auto need = [&](int c) -> size_t { return poolOff + (size_t)c * 15 * SDb + (1u << 20); };
  int C = (ws_size >= need(4)) ? 4 : (ws_size >= need(2)) ? 2 : 1;

  uint8_t* pool = base + poolOff;
  // pool phase layout
  f16* h0 = (f16*)pool;
  f16* h1 = h0 + (size_t)C * SDsz;
  f16* h2 = h1 + (size_t)C * SDsz;
  uint8_t* Rc = pool + (size_t)3 * C * SDb;   // 6C*SDb region
  uint8_t* Rq = Rc + (size_t)6 * C * SDb;     // 6C*SDb region
  // Rc phase 1: comp planes
  f16* comp0 = (f16*)Rc;
  f16* comp1 = comp0 + (size_t)3 * C * SDsz;
  // Rc phase 2: scores f32 + vT planes
  float* scores = (float*)Rc;
  f16* vT0 = (f16*)(Rc + (size_t)C * SSsz * 4);
  f16* vT1 = vT0 + (size_t)C * SDsz;
  // Rc phase 3 (over scores region): ao planes + co
  f16* ao0 = (f16*)Rc;
  f16* ao1 = ao0 + (size_t)C * SDsz;
  f16* ao2 = ao1 + (size_t)C * SDsz;
  f16* co  = ao2 + (size_t)C * SDsz;
  // Rq: qkv planes (q0,q1,k0,k1,v0,v1), later attn planes over q/k part
  f16* qkvb = (f16*)Rq;
  f16* a0 = (f16*)Rq;
  f16* a1 = a0 + (size_t)C * SSsz;
  // P0 overlay at pool start (consumed before loop)
  f16* ip0 = (f16*)pool;
  f16* ip1 = ip0 + 4 * MIsz;
  f16* pt0 = ip1 + 4 * MIsz;
  f16* pt1 = pt0 + 4 * MIsz;
  float* prc = (float*)(pool + 4 * (4 * MIsz * 2));

  k_cost<<<dim3(4), dim3(256), 0, stream>>>(gate, cost);
  k_split2<<<dim3(1024), dim3(256), 0, stream>>>(mu_w, w0, w1, MIsz);       // 4M elems = 1M float4
  k_split2<<<dim3(1024), dim3(256), 0, stream>>>(in_proto, ip0, ip1, MIsz);
  k_split2<<<dim3(1024), dim3(256), 0, stream>>>(pt_w, pt0, pt1, MIsz);
  k_prc<<<dim3(8, 8, 4), dim3(256), 0, stream>>>(ip0, ip1, pt0, pt1, prc);
  k_pln3<<<dim3(4096), dim3(256), 0, stream>>>(prc, proto_w, pln_g, pln_b, ps0, ps1, ps2);

  for (int b0 = 0; b0 < NBATCH; b0 += C) {
    k_ln3<<<dim3(C * Ss), dim3(256), 0, stream>>>(x, ln1_g, ln1_b, h0, h1, h2, b0);
    k_comp<<<dim3(16, 8, 3 * C), dim3(256), 0, stream>>>(h0, h1, w0, w1, mu_b, comp0, comp1, C);
    k_mv<<<dim3(16, 8, 3 * C), dim3(256), 0, stream>>>(h0, h1, h2, ps0, ps1, ps2, cost, comp0, comp1, qkvb, C);
    k_trans<<<dim3(32, 16, 2 * C), dim3(256), 0, stream>>>(qkvb, vT0, vT1, C);
    k_scores<<<dim3(16, 16, C), dim3(256), 0, stream>>>(qkvb, scores, C);
    k_softmax2<<<dim3(Ss, 1, C), dim3(256), 0, stream>>>(scores, a0, a1);
    k_pv<<<dim3(16, 8, C), dim3(256), 0, stream>>>(a0, a1, vT0, vT1, ao0, ao1, ao2);
    k_co<<<dim3(16, 8, C), dim3(256), 0, stream>>>(ao0, ao1, w0 + 3 * MIsz, w1 + 3 * MIsz, mu_b + 3 * Dd, co);
    k_mvo<<<dim3(16, 8, C), dim3(256), 0, stream>>>(ao0, ao1, ao2, ps0 + 3 * MIsz, ps1 + 3 * MIsz,
                                                    ps2 + 3 * MIsz, cost + 3 * Dd, co, x, out, b0);
  }
}